// Round 3
// baseline (1159.145 us; speedup 1.0000x reference)
//
#include <hip/hip_runtime.h>
#include <hip/hip_bf16.h>

using f16x8 = __attribute__((ext_vector_type(8))) _Float16;
using f32x4 = __attribute__((ext_vector_type(4))) float;
typedef unsigned uint4a __attribute__((ext_vector_type(4), aligned(4)));

__device__ inline void sp2(float v, unsigned short& h0, unsigned short& h1) {
    _Float16 a = (_Float16)v;
    float r = (v - (float)a) * 4096.0f;   // exact residual, scaled into f16-normal range
    _Float16 b = (_Float16)r;
    union { _Float16 f; unsigned short u; } c0, c1;
    c0.f = a; c1.f = b;
    h0 = c0.u; h1 = c1.u;
}

// fp32 -> two u16 planes (plain element order)
__global__ __launch_bounds__(256) void split_planes(const float* __restrict__ src,
        ushort* __restrict__ p0, ushort* __restrict__ p1, int n4) {
    int g = blockIdx.x * 256 + threadIdx.x;
    if (g >= n4) return;
    float4 v = reinterpret_cast<const float4*>(src)[g];
    ushort4 a, b;
    sp2(v.x, a.x, b.x); sp2(v.y, a.y, b.y);
    sp2(v.z, a.z, b.z); sp2(v.w, a.w, b.w);
    *reinterpret_cast<ushort4*>(&p0[(size_t)g * 4]) = a;
    *reinterpret_cast<ushort4*>(&p1[(size_t)g * 4]) = b;
}

// conv weights: fp32 (N,C,4) -> planes with per-channel tap order [kw1,kw2,kw0,kw3]
__global__ __launch_bounds__(256) void split_w(const float* __restrict__ w,
        ushort* __restrict__ p0, ushort* __restrict__ p1, int total) {
    int g = blockIdx.x * 256 + threadIdx.x;
    if (g >= total) return;
    float4 v = reinterpret_cast<const float4*>(w)[g];  // taps kw0..kw3
    ushort4 a, b;
    sp2(v.y, a.x, b.x);  // kw1
    sp2(v.z, a.y, b.y);  // kw2
    sp2(v.x, a.z, b.z);  // kw0
    sp2(v.w, a.w, b.w);  // kw3
    *reinterpret_cast<ushort4*>(&p0[(size_t)g * 4]) = a;
    *reinterpret_cast<ushort4*>(&p1[(size_t)g * 4]) = b;
}

// Split-fp16 MFMA gather-GEMM, pre-split planes, 2-phase pipelined.
// C[m][n] = sum_k A[m][k]*B[n][k]; 3-term split accumulation (acc0 + acc1/4096).
// gatherMode: A planes are NCH lines; per channel, tap pairs (word t) and
// perm(word t-1, word t+1), k-order [kw1,kw2,kw0,kw3] matching split_w.
__global__ __launch_bounds__(256, 2) void mfma_gemm(
    const ushort* __restrict__ A0, const ushort* __restrict__ A1,
    const ushort* __restrict__ B0, const ushort* __restrict__ B1,
    const float* __restrict__ bias,
    ushort* __restrict__ OP0, ushort* __restrict__ OP1,
    float* __restrict__ OutF,
    int M, int N, int KK, int Cc, int L, int Lout, int LoutSh,
    int gatherMode, int mode)
{
    __shared__ uint4 As4[128 * 8];   // [row][chunk] chunk = plane*4 + k/8, XOR-swizzled
    __shared__ uint4 Bs4[128 * 8];

    const int tid = threadIdx.x;
    const int m0 = blockIdx.y * 128;
    const int n0 = blockIdx.x * 128;

    const int srow = tid >> 1;
    const int kh = tid & 1;
    const int sw_s = (srow ^ (srow >> 3)) & 7;

    const int am = m0 + srow;
    const int ab = am >> LoutSh;
    const int at = am & (Lout - 1);

    const ushort* ag0 = nullptr;
    const ushort* ag1 = nullptr;
    const ushort* ad = nullptr;
    unsigned bmask = 0xffffffffu;
    if (gatherMode) {
        long long off = (long long)ab * Cc * L + 2 * at - 2;  // word t-1 base
        ag0 = A0 + off;
        ag1 = A1 + off;
        if (at == 0) bmask &= 0xffff0000u;        // elem 2t-1 = -1 -> 0
        if (at == Lout - 1) bmask &= 0x0000ffffu; // elem 2t+2 = L  -> 0
    } else {
        ad = (kh ? A1 : A0) + (size_t)am * KK;
    }
    const ushort* bd = (kh ? B1 : B0) + (size_t)(n0 + srow) * KK;

    const int lane = tid & 63;
    const int wv = tid >> 6;
    const int wr = wv >> 1, wc = wv & 1;
    const int l15 = lane & 15, lq = lane >> 4;

    f32x4 acc0[4][4] = {{{0.f}}};
    f32x4 acc1[4][4] = {{{0.f}}};

    uint4 aw[4], bw[4];

    auto loadA = [&](int k0) {
        if (gatherMode) {
            int cb_ = (k0 >> 2) + kh * 4;
#pragma unroll
            for (int q = 0; q < 2; q++) {
                const ushort* l0 = ag0 + (size_t)(cb_ + 2 * q) * L;
                const ushort* l1 = ag0 + (size_t)(cb_ + 2 * q + 1) * L;
                const ushort* l2 = ag1 + (size_t)(cb_ + 2 * q) * L;
                const ushort* l3 = ag1 + (size_t)(cb_ + 2 * q + 1) * L;
                uint4a x0 = *(const uint4a*)l0;
                uint4a x1 = *(const uint4a*)l1;
                uint4a x2 = *(const uint4a*)l2;
                uint4a x3 = *(const uint4a*)l3;
                aw[q].x = x0.y;
                aw[q].y = __builtin_amdgcn_perm(x0.z, x0.x, 0x05040302u) & bmask;
                aw[q].z = x1.y;
                aw[q].w = __builtin_amdgcn_perm(x1.z, x1.x, 0x05040302u) & bmask;
                aw[2 + q].x = x2.y;
                aw[2 + q].y = __builtin_amdgcn_perm(x2.z, x2.x, 0x05040302u) & bmask;
                aw[2 + q].z = x3.y;
                aw[2 + q].w = __builtin_amdgcn_perm(x3.z, x3.x, 0x05040302u) & bmask;
            }
        } else {
#pragma unroll
            for (int q = 0; q < 4; q++)
                aw[q] = *reinterpret_cast<const uint4*>(ad + k0 + q * 8);
        }
    };
    auto loadB = [&](int k0) {
#pragma unroll
        for (int q = 0; q < 4; q++)
            bw[q] = *reinterpret_cast<const uint4*>(bd + k0 + q * 8);
    };

    loadA(0);
    loadB(0);

    for (int k0 = 0; k0 < KK; k0 += 32) {
        __syncthreads();
        if (gatherMode) {
            As4[srow * 8 + ((2 * kh + 0) ^ sw_s)] = aw[0];
            As4[srow * 8 + ((2 * kh + 1) ^ sw_s)] = aw[1];
            As4[srow * 8 + ((4 + 2 * kh + 0) ^ sw_s)] = aw[2];
            As4[srow * 8 + ((4 + 2 * kh + 1) ^ sw_s)] = aw[3];
        } else {
#pragma unroll
            for (int q = 0; q < 4; q++)
                As4[srow * 8 + ((4 * kh + q) ^ sw_s)] = aw[q];
        }
#pragma unroll
        for (int q = 0; q < 4; q++)
            Bs4[srow * 8 + ((4 * kh + q) ^ sw_s)] = bw[q];
        __syncthreads();

        if (k0 + 32 < KK) { loadA(k0 + 32); loadB(k0 + 32); }  // prefetch under MFMA

        f16x8 a0f[4], a1f[4];
#pragma unroll
        for (int mf = 0; mf < 4; mf++) {
            int row = wr * 64 + mf * 16 + l15;
            int sw = (row ^ (row >> 3)) & 7;
            a0f[mf] = *reinterpret_cast<const f16x8*>(&As4[row * 8 + (lq ^ sw)]);
            a1f[mf] = *reinterpret_cast<const f16x8*>(&As4[row * 8 + ((4 + lq) ^ sw)]);
        }
#pragma unroll
        for (int nf = 0; nf < 4; nf++) {
            int row = wc * 64 + nf * 16 + l15;
            int sw = (row ^ (row >> 3)) & 7;
            f16x8 b0f = *reinterpret_cast<const f16x8*>(&Bs4[row * 8 + (lq ^ sw)]);
            f16x8 b1f = *reinterpret_cast<const f16x8*>(&Bs4[row * 8 + ((4 + lq) ^ sw)]);
#pragma unroll
            for (int mf = 0; mf < 4; mf++) {
                acc0[mf][nf] = __builtin_amdgcn_mfma_f32_16x16x32_f16(a0f[mf], b0f, acc0[mf][nf], 0, 0, 0);
                acc1[mf][nf] = __builtin_amdgcn_mfma_f32_16x16x32_f16(a0f[mf], b1f, acc1[mf][nf], 0, 0, 0);
                acc1[mf][nf] = __builtin_amdgcn_mfma_f32_16x16x32_f16(a1f[mf], b0f, acc1[mf][nf], 0, 0, 0);
            }
        }
    }

    const float s12 = 1.0f / 4096.0f;
    const int LoutM = Lout - 1;

    if (mode == 2) {
#pragma unroll
        for (int mf = 0; mf < 4; mf++) {
            int mb = m0 + wr * 64 + mf * 16 + lq * 4;
#pragma unroll
            for (int nf = 0; nf < 4; nf++) {
                int n = n0 + wc * 64 + nf * 16 + l15;
#pragma unroll
                for (int r = 0; r < 4; r++)
                    OutF[(size_t)(mb + r) * N + n] = acc0[mf][nf][r] + acc1[mf][nf][r] * s12;
            }
        }
    } else if (mode == 0) {
#pragma unroll
        for (int mf = 0; mf < 4; mf++) {
            int mb = m0 + wr * 64 + mf * 16 + lq * 4;
            int b = mb >> LoutSh, t = mb & LoutM;
#pragma unroll
            for (int nf = 0; nf < 4; nf++) {
                int n = n0 + wc * 64 + nf * 16 + l15;
                float bv = bias[n];
                ushort4 o0, o1;
                float v;
                v = fmaxf(acc0[mf][nf][0] + acc1[mf][nf][0] * s12 + bv, 0.f); sp2(v, o0.x, o1.x);
                v = fmaxf(acc0[mf][nf][1] + acc1[mf][nf][1] * s12 + bv, 0.f); sp2(v, o0.y, o1.y);
                v = fmaxf(acc0[mf][nf][2] + acc1[mf][nf][2] * s12 + bv, 0.f); sp2(v, o0.z, o1.z);
                v = fmaxf(acc0[mf][nf][3] + acc1[mf][nf][3] * s12 + bv, 0.f); sp2(v, o0.w, o1.w);
                size_t base = ((size_t)b * N + n) * Lout + t;
                *reinterpret_cast<ushort4*>(&OP0[base]) = o0;
                *reinterpret_cast<ushort4*>(&OP1[base]) = o1;
            }
        }
    } else {  // mode 1: fp32 NCH + packed planes [m][N]
#pragma unroll
        for (int mf = 0; mf < 4; mf++) {
            int mb = m0 + wr * 64 + mf * 16 + lq * 4;
            int b = mb >> LoutSh, t = mb & LoutM;
#pragma unroll
            for (int nf = 0; nf < 4; nf++) {
                int n = n0 + wc * 64 + nf * 16 + l15;
                float bv = bias[n];
                float4 f;
                unsigned short h0[4], h1[4];
#pragma unroll
                for (int r = 0; r < 4; r++) {
                    float v = acc0[mf][nf][r] + acc1[mf][nf][r] * s12 + bv;
                    ((float*)&f)[r] = v;
                    sp2(v, h0[r], h1[r]);
                }
                *reinterpret_cast<float4*>(&OutF[((size_t)b * N + n) * Lout + t]) = f;
#pragma unroll
                for (int r = 0; r < 4; r++) {
                    OP0[(size_t)(mb + r) * N + n] = h0[r];
                    OP1[(size_t)(mb + r) * N + n] = h1[r];
                }
            }
        }
    }
}

// ||codebook_n||^2, one wave per row (fp32 exact)
__global__ __launch_bounds__(64) void cb_norm(const float* __restrict__ cb,
                                              float* __restrict__ cn2) {
    int n = blockIdx.x;
    int lane = threadIdx.x;
    float s = 0.f;
    for (int d = lane; d < 512; d += 64) {
        float v = cb[(size_t)n * 512 + d];
        s += v * v;
    }
#pragma unroll
    for (int off = 32; off; off >>= 1) s += __shfl_down(s, off);
    if (lane == 0) cn2[n] = s;
}

// argmin over (cn2[n] - 2*S[r][n]); one wave per row, first-occurrence ties
__global__ __launch_bounds__(256) void argmin_k(const float* __restrict__ S,
                                                const float* __restrict__ cn2,
                                                float* __restrict__ idxf,
                                                int* __restrict__ idxi, int rows) {
    int wid = threadIdx.x >> 6;
    int lane = threadIdx.x & 63;
    int r = blockIdx.x * 4 + wid;
    if (r >= rows) return;
    const float* srow = S + (size_t)r * 1024;
    float best = INFINITY;
    int bi = 0;
#pragma unroll
    for (int it = 0; it < 4; it++) {
        int nb = it * 256 + lane * 4;
        float4 s4 = *reinterpret_cast<const float4*>(&srow[nb]);
        float4 c4 = *reinterpret_cast<const float4*>(&cn2[nb]);
        float v;
        v = c4.x - 2.f * s4.x; if (v < best) { best = v; bi = nb + 0; }
        v = c4.y - 2.f * s4.y; if (v < best) { best = v; bi = nb + 1; }
        v = c4.z - 2.f * s4.z; if (v < best) { best = v; bi = nb + 2; }
        v = c4.w - 2.f * s4.w; if (v < best) { best = v; bi = nb + 3; }
    }
#pragma unroll
    for (int off = 32; off; off >>= 1) {
        float ov = __shfl_down(best, off);
        int oi = __shfl_down(bi, off);
        if (ov < best || (ov == best && oi < bi)) { best = ov; bi = oi; }
    }
    if (lane == 0) {
        idxf[r] = (float)bi;
        idxi[r] = bi;
    }
}

// z_q[r][:] = codebook[idx[r]][:]
__global__ __launch_bounds__(256) void gather_k(const int* __restrict__ idx,
                                                const float* __restrict__ cb,
                                                float* __restrict__ zq, int total4) {
    int g = blockIdx.x * 256 + threadIdx.x;
    if (g >= total4) return;
    int r = g >> 7;
    int d4 = g & 127;
    int id = idx[r];
    *reinterpret_cast<float4*>(&zq[(size_t)r * 512 + (size_t)d4 * 4]) =
        *reinterpret_cast<const float4*>(&cb[(size_t)id * 512 + (size_t)d4 * 4]);
}

extern "C" void kernel_launch(void* const* d_in, const int* in_sizes, int n_in,
                              void* d_out, int out_size, void* d_ws, size_t ws_size,
                              hipStream_t stream) {
    const float* x  = (const float*)d_in[0];  // (32, 256, 2048)
    const float* w1 = (const float*)d_in[1];  // (1024, 256, 4)
    const float* b1 = (const float*)d_in[2];
    const float* w2 = (const float*)d_in[3];  // (512, 1024, 4)
    const float* b2 = (const float*)d_in[4];
    const float* cb = (const float*)d_in[5];  // (1024, 512)
    float* out = (float*)d_out;

    const int B = 32, Cin = 256, T = 2048, H = 1024, D = 512, Kc = 1024;
    const int T1 = 1024, T2 = 512;

    float* zq_out  = out;                       // (B*T2, D)
    float* idx_out = out + (size_t)B * T2 * D;  // (B*T2,)
    float* ze_out  = idx_out + (size_t)B * T2;  // (B, D, T2)

    // ws layout in u16 units; 64B head guard for t=0 gather underread
    ushort* wsb = (ushort*)d_ws;
    size_t cur = 32;
    auto alloc16 = [&](size_t n) {
        ushort* p = wsb + cur;
        cur += (n + 31) & ~(size_t)31;
        return p;
    };

    ushort* w1p0 = alloc16((size_t)H * Cin * 4);
    ushort* w1p1 = alloc16((size_t)H * Cin * 4);
    ushort* w2p0 = alloc16((size_t)D * H * 4);
    ushort* w2p1 = alloc16((size_t)D * H * 4);
    ushort* cbp0 = alloc16((size_t)Kc * D);
    ushort* cbp1 = alloc16((size_t)Kc * D);
    float* cn2   = (float*)alloc16(2 * (size_t)Kc);
    int* idx_ws  = (int*)alloc16(2 * (size_t)B * T2);

    size_t fixed = cur;
    int NB = 32;
    while (NB > 1 &&
           (fixed + 2 * ((size_t)NB * Cin * T + (size_t)NB * H * T1 + (size_t)NB * T2 * D) + 128)
               * 2 > ws_size)
        NB >>= 1;

    // xp planes contiguous so S (fp32 scores) can overlay them exactly
    ushort* xp0 = alloc16(2 * (size_t)NB * Cin * T);
    ushort* xp1 = xp0 + (size_t)NB * Cin * T;
    ushort* hp0 = alloc16((size_t)NB * H * T1);
    ushort* hp1 = alloc16((size_t)NB * H * T1);
    ushort* zp0 = alloc16((size_t)NB * T2 * D);
    ushort* zp1 = alloc16((size_t)NB * T2 * D);
    float* S = (float*)xp0;  // nb*T2*Kc fp32 == xp0+xp1 footprint exactly

    split_w<<<(H * Cin + 255) / 256, 256, 0, stream>>>(w1, w1p0, w1p1, H * Cin);
    split_w<<<(D * H + 255) / 256, 256, 0, stream>>>(w2, w2p0, w2p1, D * H);
    split_planes<<<(Kc * D / 4 + 255) / 256, 256, 0, stream>>>(cb, cbp0, cbp1, Kc * D / 4);
    cb_norm<<<Kc, 64, 0, stream>>>(cb, cn2);

    for (int b0 = 0; b0 < B; b0 += NB) {
        int nb = (B - b0 < NB) ? (B - b0) : NB;

        split_planes<<<(nb * Cin * T / 4 + 255) / 256, 256, 0, stream>>>(
            x + (size_t)b0 * Cin * T, xp0, xp1, nb * Cin * T / 4);

        // conv1 + relu -> hp planes (NCH)
        mfma_gemm<<<dim3(H / 128, nb * T1 / 128), 256, 0, stream>>>(
            xp0, xp1, w1p0, w1p1, b1, hp0, hp1, nullptr,
            nb * T1, H, Cin * 4, Cin, T, T1, 10, 1, 0);

        // conv2 -> ze fp32 NCH + zp planes [m][D]
        mfma_gemm<<<dim3(D / 128, nb * T2 / 128), 256, 0, stream>>>(
            hp0, hp1, w2p0, w2p1, b2, zp0, zp1, ze_out + (size_t)b0 * D * T2,
            nb * T2, D, H * 4, H, T1, T2, 9, 1, 1);

        // scores S[m][n] = z . cb
        mfma_gemm<<<dim3(Kc / 128, nb * T2 / 128), 256, 0, stream>>>(
            zp0, zp1, cbp0, cbp1, nullptr, nullptr, nullptr, S,
            nb * T2, Kc, D, 0, 0, T2, 9, 0, 2);

        argmin_k<<<(nb * T2 + 3) / 4, 256, 0, stream>>>(
            S, cn2, idx_out + (size_t)b0 * T2, idx_ws, nb * T2);

        gather_k<<<(nb * T2 * D / 4 + 255) / 256, 256, 0, stream>>>(
            idx_ws, cb, zq_out + (size_t)b0 * T2 * D, nb * T2 * D / 4);
    }
}

// Round 4
// 1101.904 us; speedup vs baseline: 1.0519x; 1.0519x over previous
//
#include <hip/hip_runtime.h>
#include <hip/hip_bf16.h>

using f16x8 = __attribute__((ext_vector_type(8))) _Float16;
using f32x4 = __attribute__((ext_vector_type(4))) float;

union PackU { unsigned u; _Float16 h[2]; };

__device__ inline unsigned split_pack(float v) {
    _Float16 h0 = (_Float16)v;
    float r = (v - (float)h0) * 4096.0f;   // exact; scaled residual stays fp16-normal
    PackU p; p.h[0] = h0; p.h[1] = (_Float16)r;
    return p.u;
}

// fp32 -> packed u32 {h0, h1} (element order preserved)
__global__ __launch_bounds__(256) void split_kernel(const float* __restrict__ src,
                                                    unsigned* __restrict__ dst, int n4) {
    int g = blockIdx.x * 256 + threadIdx.x;
    if (g >= n4) return;
    float4 v = reinterpret_cast<const float4*>(src)[g];
    uint4 o;
    o.x = split_pack(v.x); o.y = split_pack(v.y);
    o.z = split_pack(v.z); o.w = split_pack(v.w);
    reinterpret_cast<uint4*>(dst)[g] = o;
}

// fp32 -> two separated u16 planes (element order preserved)
__global__ __launch_bounds__(256) void split_planes(const float* __restrict__ src,
        ushort* __restrict__ p0, ushort* __restrict__ p1, int n4) {
    int g = blockIdx.x * 256 + threadIdx.x;
    if (g >= n4) return;
    float4 v = reinterpret_cast<const float4*>(src)[g];
    ushort4 a, b;
    unsigned u;
    u = split_pack(v.x); a.x = (ushort)u; b.x = (ushort)(u >> 16);
    u = split_pack(v.y); a.y = (ushort)u; b.y = (ushort)(u >> 16);
    u = split_pack(v.z); a.z = (ushort)u; b.z = (ushort)(u >> 16);
    u = split_pack(v.w); a.w = (ushort)u; b.w = (ushort)(u >> 16);
    *reinterpret_cast<ushort4*>(&p0[(size_t)g * 4]) = a;
    *reinterpret_cast<ushort4*>(&p1[(size_t)g * 4]) = b;
}

// Split-fp16 MFMA gather-GEMM. A: packed u32 plane-pairs. B: separated u16 planes.
// C[m][n] = sum_kk A[m][kk] * B[n][kk]; 3-term split accumulation.
// Grid: (M/128, N/128) -- m-major flat order => XCD = mblk%8 (A-panel L2 locality).
// mode 0: OutP NCH packed u32 = split(relu(acc+bias))   (conv1 -> hp)
// mode 1: OutF NCH fp32 (+bias) AND OutP[m][N] packed   (conv2 -> ze, zp)
// mode 2: OutF[m][N] fp32                               (scores)
__global__ __launch_bounds__(256, 2) void mfma_gemm(
    const unsigned* __restrict__ Ap,
    const ushort* __restrict__ B0, const ushort* __restrict__ B1,
    const float* __restrict__ bias,
    unsigned* __restrict__ OutP, float* __restrict__ OutF,
    int M, int N, int KK, int Cc, int L, int Lout, int LoutSh,
    int gatherMode, int mode)
{
    __shared__ uint4 As4[128 * 8];   // [row][chunk] chunk = plane*4 + k/8, XOR-swizzled
    __shared__ uint4 Bs4[128 * 8];

    const int tid = threadIdx.x;
    const int m0 = blockIdx.x * 128;
    const int n0 = blockIdx.y * 128;

    const int srow = tid >> 1;
    const int kh = tid & 1;
    const int sw_s = srow & 7;

    const int am = m0 + srow;
    const int ab = am >> LoutSh;
    const int at = am & (Lout - 1);
    const unsigned* aprow = Ap + (size_t)ab * Cc * L;
    const int ai0 = 2 * at - 1;
    const unsigned* adir = Ap + (size_t)am * KK;
    const ushort* bd = (kh ? B1 : B0) + (size_t)(n0 + srow) * KK;

    const int lane = tid & 63;
    const int wv = tid >> 6;
    const int wr = wv >> 1, wc = wv & 1;
    const int l15 = lane & 15, lq = lane >> 4;

    f32x4 acc0[4][4] = {{{0.f}}};
    f32x4 acc1[4][4] = {{{0.f}}};

    uint4 pa[4], bw[4];

    auto loadA = [&](int k0) {
        if (gatherMode) {
            int cbase = (k0 >> 2) + kh * 4;
#pragma unroll
            for (int cl = 0; cl < 4; cl++) {
                const unsigned* base = aprow + (size_t)(cbase + cl) * L;
                unsigned q0 = 0, q3 = 0;
                if (ai0 >= 0) q0 = base[ai0];           // only t==0 pads
                unsigned q1 = base[ai0 + 1];
                unsigned q2 = base[ai0 + 2];
                if (ai0 + 3 < L) q3 = base[ai0 + 3];    // only t==Lout-1 pads
                pa[cl].x = q0; pa[cl].y = q1; pa[cl].z = q2; pa[cl].w = q3;
            }
        } else {
            const uint4* s = reinterpret_cast<const uint4*>(adir + k0 + kh * 16);
#pragma unroll
            for (int q = 0; q < 4; q++) pa[q] = s[q];
        }
    };
    auto loadB = [&](int k0) {
#pragma unroll
        for (int q = 0; q < 4; q++)
            bw[q] = *reinterpret_cast<const uint4*>(bd + k0 + q * 8);  // 16B aligned
    };

    loadA(0);
    loadB(0);

    for (int k0 = 0; k0 < KK; k0 += 32) {
        __syncthreads();   // previous tile's LDS reads complete

        // B: already plane-separated, direct b128 stores (no repack)
#pragma unroll
        for (int q = 0; q < 4; q++)
            Bs4[srow * 8 + ((4 * kh + q) ^ sw_s)] = bw[q];

        // A: split packed u32 -> plane chunks via v_perm (2 ops/pair)
#pragma unroll
        for (int ch = 0; ch < 2; ch++) {
            uint4 w0, w1;
            unsigned* W0 = (unsigned*)&w0; unsigned* W1 = (unsigned*)&w1;
#pragma unroll
            for (int j = 0; j < 4; j++) {
                int e0 = ch * 8 + 2 * j, e1 = e0 + 1;
                unsigned lo = ((const unsigned*)&pa[e0 >> 2])[e0 & 3];
                unsigned hi = ((const unsigned*)&pa[e1 >> 2])[e1 & 3];
                W0[j] = __builtin_amdgcn_perm(hi, lo, 0x05040100u); // {lo.h0, hi.h0}
                W1[j] = __builtin_amdgcn_perm(hi, lo, 0x07060302u); // {lo.h1, hi.h1}
            }
            int kc = kh * 2 + ch;
            As4[srow * 8 + (kc ^ sw_s)] = w0;
            As4[srow * 8 + ((4 + kc) ^ sw_s)] = w1;
        }
        __syncthreads();

        // raw prefetch of next tile -- no dependent VALU until next iter's repack,
        // so the vmcnt wait lands after this iteration's MFMA cluster
        if (k0 + 32 < KK) { loadA(k0 + 32); loadB(k0 + 32); }

        f16x8 a0f[4], a1f[4];
#pragma unroll
        for (int mf = 0; mf < 4; mf++) {
            int row = wr * 64 + mf * 16 + l15;
            int sw = row & 7;
            a0f[mf] = *reinterpret_cast<const f16x8*>(&As4[row * 8 + (lq ^ sw)]);
            a1f[mf] = *reinterpret_cast<const f16x8*>(&As4[row * 8 + ((4 + lq) ^ sw)]);
        }
#pragma unroll
        for (int nf = 0; nf < 4; nf++) {
            int row = wc * 64 + nf * 16 + l15;
            int sw = row & 7;
            f16x8 b0f = *reinterpret_cast<const f16x8*>(&Bs4[row * 8 + (lq ^ sw)]);
            f16x8 b1f = *reinterpret_cast<const f16x8*>(&Bs4[row * 8 + ((4 + lq) ^ sw)]);
#pragma unroll
            for (int mf = 0; mf < 4; mf++) {
                acc0[mf][nf] = __builtin_amdgcn_mfma_f32_16x16x32_f16(a0f[mf], b0f, acc0[mf][nf], 0, 0, 0);
                acc1[mf][nf] = __builtin_amdgcn_mfma_f32_16x16x32_f16(a0f[mf], b1f, acc1[mf][nf], 0, 0, 0);
                acc1[mf][nf] = __builtin_amdgcn_mfma_f32_16x16x32_f16(a1f[mf], b0f, acc1[mf][nf], 0, 0, 0);
            }
        }
    }

    const float s12 = 1.0f / 4096.0f;
    const int LoutM = Lout - 1;

    if (mode == 2) {
#pragma unroll
        for (int mf = 0; mf < 4; mf++) {
            int mb = m0 + wr * 64 + mf * 16 + lq * 4;
#pragma unroll
            for (int nf = 0; nf < 4; nf++) {
                int n = n0 + wc * 64 + nf * 16 + l15;
#pragma unroll
                for (int r = 0; r < 4; r++)
                    OutF[(size_t)(mb + r) * N + n] = acc0[mf][nf][r] + acc1[mf][nf][r] * s12;
            }
        }
    } else if (mode == 0) {
#pragma unroll
        for (int mf = 0; mf < 4; mf++) {
            int mb = m0 + wr * 64 + mf * 16 + lq * 4;
            int b = mb >> LoutSh, t = mb & LoutM;
#pragma unroll
            for (int nf = 0; nf < 4; nf++) {
                int n = n0 + wc * 64 + nf * 16 + l15;
                float bv = bias[n];
                uint4 o;
                unsigned* O = (unsigned*)&o;
#pragma unroll
                for (int r = 0; r < 4; r++) {
                    float v = acc0[mf][nf][r] + acc1[mf][nf][r] * s12 + bv;
                    v = fmaxf(v, 0.f);
                    O[r] = split_pack(v);
                }
                *reinterpret_cast<uint4*>(&OutP[((size_t)b * N + n) * Lout + t]) = o;
            }
        }
    } else {  // mode 1: fp32 NCH + packed u32 [m][N]
#pragma unroll
        for (int mf = 0; mf < 4; mf++) {
            int mb = m0 + wr * 64 + mf * 16 + lq * 4;
            int b = mb >> LoutSh, t = mb & LoutM;
#pragma unroll
            for (int nf = 0; nf < 4; nf++) {
                int n = n0 + wc * 64 + nf * 16 + l15;
                float bv = bias[n];
                float4 f;
                unsigned O[4];
#pragma unroll
                for (int r = 0; r < 4; r++) {
                    float v = acc0[mf][nf][r] + acc1[mf][nf][r] * s12 + bv;
                    ((float*)&f)[r] = v;
                    O[r] = split_pack(v);
                }
                *reinterpret_cast<float4*>(&OutF[((size_t)b * N + n) * Lout + t]) = f;
#pragma unroll
                for (int r = 0; r < 4; r++)
                    OutP[(size_t)(mb + r) * N + n] = O[r];
            }
        }
    }
}

// ||codebook_n||^2, one wave per row (fp32 exact)
__global__ __launch_bounds__(64) void cb_norm(const float* __restrict__ cb,
                                              float* __restrict__ cn2) {
    int n = blockIdx.x;
    int lane = threadIdx.x;
    float s = 0.f;
    for (int d = lane; d < 512; d += 64) {
        float v = cb[(size_t)n * 512 + d];
        s += v * v;
    }
#pragma unroll
    for (int off = 32; off; off >>= 1) s += __shfl_down(s, off);
    if (lane == 0) cn2[n] = s;
}

// argmin over (cn2[n] - 2*S[r][n]); one wave per row, first-occurrence ties
__global__ __launch_bounds__(256) void argmin_k(const float* __restrict__ S,
                                                const float* __restrict__ cn2,
                                                float* __restrict__ idxf,
                                                int* __restrict__ idxi, int rows) {
    int wid = threadIdx.x >> 6;
    int lane = threadIdx.x & 63;
    int r = blockIdx.x * 4 + wid;
    if (r >= rows) return;
    const float* srow = S + (size_t)r * 1024;
    float best = INFINITY;
    int bi = 0;
#pragma unroll
    for (int it = 0; it < 4; it++) {
        int nb = it * 256 + lane * 4;
        float4 s4 = *reinterpret_cast<const float4*>(&srow[nb]);
        float4 c4 = *reinterpret_cast<const float4*>(&cn2[nb]);
        float v;
        v = c4.x - 2.f * s4.x; if (v < best) { best = v; bi = nb + 0; }
        v = c4.y - 2.f * s4.y; if (v < best) { best = v; bi = nb + 1; }
        v = c4.z - 2.f * s4.z; if (v < best) { best = v; bi = nb + 2; }
        v = c4.w - 2.f * s4.w; if (v < best) { best = v; bi = nb + 3; }
    }
#pragma unroll
    for (int off = 32; off; off >>= 1) {
        float ov = __shfl_down(best, off);
        int oi = __shfl_down(bi, off);
        if (ov < best || (ov == best && oi < bi)) { best = ov; bi = oi; }
    }
    if (lane == 0) {
        idxf[r] = (float)bi;
        idxi[r] = bi;
    }
}

// z_q[r][:] = codebook[idx[r]][:]
__global__ __launch_bounds__(256) void gather_k(const int* __restrict__ idx,
                                                const float* __restrict__ cb,
                                                float* __restrict__ zq, int total4) {
    int g = blockIdx.x * 256 + threadIdx.x;
    if (g >= total4) return;
    int r = g >> 7;
    int d4 = g & 127;
    int id = idx[r];
    *reinterpret_cast<float4*>(&zq[(size_t)r * 512 + (size_t)d4 * 4]) =
        *reinterpret_cast<const float4*>(&cb[(size_t)id * 512 + (size_t)d4 * 4]);
}

extern "C" void kernel_launch(void* const* d_in, const int* in_sizes, int n_in,
                              void* d_out, int out_size, void* d_ws, size_t ws_size,
                              hipStream_t stream) {
    const float* x  = (const float*)d_in[0];  // (32, 256, 2048)
    const float* w1 = (const float*)d_in[1];  // (1024, 256, 4)
    const float* b1 = (const float*)d_in[2];
    const float* w2 = (const float*)d_in[3];  // (512, 1024, 4)
    const float* b2 = (const float*)d_in[4];
    const float* cb = (const float*)d_in[5];  // (1024, 512)
    float* out = (float*)d_out;

    const int B = 32, Cin = 256, T = 2048, H = 1024, D = 512, Kc = 1024;
    const int T1 = 1024, T2 = 512;

    float* zq_out  = out;                       // (B*T2, D)
    float* idx_out = out + (size_t)B * T2 * D;  // (B*T2,)
    float* ze_out  = idx_out + (size_t)B * T2;  // (B, D, T2)

    // ws layout in u32 units
    unsigned* wsb = (unsigned*)d_ws;
    size_t cur = 0;
    auto alloc32 = [&](size_t n) {
        unsigned* p = wsb + cur;
        cur += (n + 15) & ~(size_t)15;
        return p;
    };

    ushort* w1p0 = (ushort*)alloc32((size_t)H * Cin * 2);   // H*Cin*4 u16
    ushort* w1p1 = (ushort*)alloc32((size_t)H * Cin * 2);
    ushort* w2p0 = (ushort*)alloc32((size_t)D * H * 2);
    ushort* w2p1 = (ushort*)alloc32((size_t)D * H * 2);
    ushort* cbp0 = (ushort*)alloc32((size_t)Kc * D / 2);
    ushort* cbp1 = (ushort*)alloc32((size_t)Kc * D / 2);
    float* cn2   = (float*)alloc32(Kc);
    int* idx_ws  = (int*)alloc32((size_t)B * T2);

    size_t fixed = cur;
    int NB = 32;
    while (NB > 1 &&
           (fixed + (size_t)NB * ((size_t)Cin * T + (size_t)H * T1 + (size_t)T2 * D) + 64)
               * 4 > ws_size)
        NB >>= 1;

    unsigned* xp = alloc32((size_t)NB * Cin * T);
    unsigned* hp = alloc32((size_t)NB * H * T1);
    unsigned* zp = alloc32((size_t)NB * T2 * D);
    float* S = (float*)hp;   // nb*T2*Kc fp32 = 64MB <= hp footprint 128MB; hp dead then

    split_planes<<<(H * Cin + 255) / 256, 256, 0, stream>>>(w1, w1p0, w1p1, H * Cin);
    split_planes<<<(D * H + 255) / 256, 256, 0, stream>>>(w2, w2p0, w2p1, D * H);
    split_planes<<<(Kc * D / 4 + 255) / 256, 256, 0, stream>>>(cb, cbp0, cbp1, Kc * D / 4);
    cb_norm<<<Kc, 64, 0, stream>>>(cb, cn2);

    for (int b0 = 0; b0 < B; b0 += NB) {
        int nb = (B - b0 < NB) ? (B - b0) : NB;

        split_kernel<<<(nb * Cin * T / 4 + 255) / 256, 256, 0, stream>>>(
            x + (size_t)b0 * Cin * T, xp, nb * Cin * T / 4);

        // conv1 + relu -> hp (packed u32 NCH)
        mfma_gemm<<<dim3(nb * T1 / 128, H / 128), 256, 0, stream>>>(
            xp, w1p0, w1p1, b1, hp, nullptr,
            nb * T1, H, Cin * 4, Cin, T, T1, 10, 1, 0);

        // conv2 -> ze fp32 NCH + zp packed [m][D]
        mfma_gemm<<<dim3(nb * T2 / 128, D / 128), 256, 0, stream>>>(
            hp, w2p0, w2p1, b2, zp, ze_out + (size_t)b0 * D * T2,
            nb * T2, D, H * 4, H, T1, T2, 9, 1, 1);

        // scores S[m][n] = z . cb
        mfma_gemm<<<dim3(nb * T2 / 128, Kc / 128), 256, 0, stream>>>(
            zp, cbp0, cbp1, nullptr, nullptr, S,
            nb * T2, Kc, D, 0, 0, T2, 9, 0, 2);

        argmin_k<<<(nb * T2 + 3) / 4, 256, 0, stream>>>(
            S, cn2, idx_out + (size_t)b0 * T2, idx_ws, nb * T2);

        gather_k<<<(nb * T2 * D / 4 + 255) / 256, 256, 0, stream>>>(
            idx_ws, cb, zq_out + (size_t)b0 * T2 * D, nb * T2 * D / 4);
    }
}

// Round 5
// 618.106 us; speedup vs baseline: 1.8753x; 1.7827x over previous
//
#include <hip/hip_runtime.h>
#include <hip/hip_bf16.h>

using f16x8 = __attribute__((ext_vector_type(8))) _Float16;
using f32x4 = __attribute__((ext_vector_type(4))) float;

union PackU { unsigned u; _Float16 h[2]; };

__device__ inline unsigned split_pack(float v) {
    _Float16 h0 = (_Float16)v;
    float r = (v - (float)h0) * 4096.0f;   // exact; scaled residual stays fp16-normal
    PackU p; p.h[0] = h0; p.h[1] = (_Float16)r;
    return p.u;
}

// fp32 -> packed {f16 hi, f16 lo*4096} planes
__global__ __launch_bounds__(256) void split_kernel(const float* __restrict__ src,
                                                    unsigned* __restrict__ dst, int n4) {
    int g = blockIdx.x * 256 + threadIdx.x;
    if (g >= n4) return;
    float4 v = reinterpret_cast<const float4*>(src)[g];
    uint4 o;
    o.x = split_pack(v.x); o.y = split_pack(v.y);
    o.z = split_pack(v.z); o.w = split_pack(v.w);
    reinterpret_cast<uint4*>(dst)[g] = o;
}

#define BMt 128
#define BNt 128
#define BKt 32

// Unified split-fp16 MFMA gather-GEMM (round-2 structure).
// C[m][n] = sum_kk A[m][kk] * B[n][kk]   (B row-major [N][KK])
// gather: A[m][kk] = Ap[b][c][i], kk=(c,kw), i=2t-1+kw, m=(b,t)
// mode 0: OutP[b][n][Lout]+t = split_pack(relu(acc+bias))      (conv1 -> hp)
// mode 1: OutF NCH fp32 (+bias) AND OutP[m][N] packed          (conv2 -> ze, zp)
// mode 2: OutF[m][N] fp32                                      (scores)
__global__ __launch_bounds__(256, 2) void mfma_gemm(
    const unsigned* __restrict__ Ap, const unsigned* __restrict__ Bp,
    const float* __restrict__ bias,
    unsigned* __restrict__ OutP, float* __restrict__ OutF,
    int M, int N, int KK, int Cc, int L, int Lout, int LoutSh,
    int gatherMode, int mode)
{
    __shared__ uint4 As4[BMt * 8];   // [row][chunk] chunk = plane*4 + k/8, XOR-swizzled
    __shared__ uint4 Bs4[BNt * 8];

    const int tid = threadIdx.x;
    const int m0 = blockIdx.y * BMt;
    const int n0 = blockIdx.x * BNt;

    // staging mapping: thread -> (row, k-half)
    const int srow = tid >> 1;
    const int kh = tid & 1;
    const int am = m0 + srow;
    const int ab = am >> LoutSh;
    const int at = am & (Lout - 1);
    const unsigned* aprow = Ap + (size_t)ab * Cc * L;
    const int ai0 = 2 * at - 1;
    const unsigned* adir = Ap + (size_t)am * KK;
    const unsigned* brow = Bp + (size_t)(n0 + srow) * KK;

    // wave mapping
    const int lane = tid & 63;
    const int wv = tid >> 6;
    const int wr = wv >> 1, wc = wv & 1;
    const int l15 = lane & 15, lq = lane >> 4;

    f32x4 acc0[4][4] = {{{0.f}}};
    f32x4 acc1[4][4] = {{{0.f}}};

    for (int k0 = 0; k0 < KK; k0 += BKt) {
        uint4 pa[4], pb[4];
        if (gatherMode) {
            int cbase = (k0 >> 2) + kh * 4;
#pragma unroll
            for (int cl = 0; cl < 4; cl++) {
                const unsigned* base = aprow + (size_t)(cbase + cl) * L;
                unsigned q0 = 0, q3 = 0;
                if (ai0 >= 0) q0 = base[ai0];           // only t==0 pads
                unsigned q1 = base[ai0 + 1];            // always in [0, L-2]
                unsigned q2 = base[ai0 + 2];            // always in [1, L-1]
                if (ai0 + 3 < L) q3 = base[ai0 + 3];    // only t==Lout-1 pads
                pa[cl].x = q0; pa[cl].y = q1; pa[cl].z = q2; pa[cl].w = q3;
            }
        } else {
            const uint4* s = reinterpret_cast<const uint4*>(adir + k0 + kh * 16);
            pa[0] = s[0]; pa[1] = s[1]; pa[2] = s[2]; pa[3] = s[3];
        }
        {
            const uint4* s = reinterpret_cast<const uint4*>(brow + k0 + kh * 16);
            pb[0] = s[0]; pb[1] = s[1]; pb[2] = s[2]; pb[3] = s[3];
        }

        __syncthreads();   // previous tile's reads complete before overwrite

        // split planes and write (16 elems = 2 chunks per plane)
        // v_perm replaces the 4-op mask/shift per pair (validated in round 4):
        //   perm(hi, lo, 0x05040100) = {hi.h0, lo.h0}  (plane 0)
        //   perm(hi, lo, 0x07060302) = {hi.h1, lo.h1}  (plane 1)
#pragma unroll
        for (int ch = 0; ch < 2; ch++) {
            uint4 w0, w1, v0, v1;
            unsigned* W0 = (unsigned*)&w0; unsigned* W1 = (unsigned*)&w1;
            unsigned* V0 = (unsigned*)&v0; unsigned* V1 = (unsigned*)&v1;
#pragma unroll
            for (int j = 0; j < 4; j++) {
                int e0 = ch * 8 + 2 * j, e1 = e0 + 1;
                unsigned lo = ((const unsigned*)&pa[e0 >> 2])[e0 & 3];
                unsigned hi = ((const unsigned*)&pa[e1 >> 2])[e1 & 3];
                W0[j] = __builtin_amdgcn_perm(hi, lo, 0x05040100u);
                W1[j] = __builtin_amdgcn_perm(hi, lo, 0x07060302u);
                lo = ((const unsigned*)&pb[e0 >> 2])[e0 & 3];
                hi = ((const unsigned*)&pb[e1 >> 2])[e1 & 3];
                V0[j] = __builtin_amdgcn_perm(hi, lo, 0x05040100u);
                V1[j] = __builtin_amdgcn_perm(hi, lo, 0x07060302u);
            }
            int kc = kh * 2 + ch;
            int sw = srow & 7;
            As4[srow * 8 + ((kc) ^ sw)] = w0;
            As4[srow * 8 + ((4 + kc) ^ sw)] = w1;
            Bs4[srow * 8 + ((kc) ^ sw)] = v0;
            Bs4[srow * 8 + ((4 + kc) ^ sw)] = v1;
        }

        __syncthreads();

        f16x8 a0f[4], a1f[4], b0f[4], b1f[4];
#pragma unroll
        for (int mf = 0; mf < 4; mf++) {
            int row = wr * 64 + mf * 16 + l15;
            int sw = row & 7;
            a0f[mf] = *reinterpret_cast<const f16x8*>(&As4[row * 8 + (lq ^ sw)]);
            a1f[mf] = *reinterpret_cast<const f16x8*>(&As4[row * 8 + ((4 + lq) ^ sw)]);
        }
#pragma unroll
        for (int nf = 0; nf < 4; nf++) {
            int row = wc * 64 + nf * 16 + l15;
            int sw = row & 7;
            b0f[nf] = *reinterpret_cast<const f16x8*>(&Bs4[row * 8 + (lq ^ sw)]);
            b1f[nf] = *reinterpret_cast<const f16x8*>(&Bs4[row * 8 + ((4 + lq) ^ sw)]);
        }
#pragma unroll
        for (int mf = 0; mf < 4; mf++)
#pragma unroll
            for (int nf = 0; nf < 4; nf++) {
                acc0[mf][nf] = __builtin_amdgcn_mfma_f32_16x16x32_f16(
                    a0f[mf], b0f[nf], acc0[mf][nf], 0, 0, 0);
                acc1[mf][nf] = __builtin_amdgcn_mfma_f32_16x16x32_f16(
                    a0f[mf], b1f[nf], acc1[mf][nf], 0, 0, 0);
                acc1[mf][nf] = __builtin_amdgcn_mfma_f32_16x16x32_f16(
                    a1f[mf], b0f[nf], acc1[mf][nf], 0, 0, 0);
            }
    }

    const float s12 = 1.0f / 4096.0f;
    const int LoutM = Lout - 1;

    if (mode == 2) {
#pragma unroll
        for (int mf = 0; mf < 4; mf++) {
            int mb = m0 + wr * 64 + mf * 16 + lq * 4;
#pragma unroll
            for (int nf = 0; nf < 4; nf++) {
                int n = n0 + wc * 64 + nf * 16 + l15;
#pragma unroll
                for (int r = 0; r < 4; r++) {
                    float v = acc0[mf][nf][r] + acc1[mf][nf][r] * s12;
                    OutF[(size_t)(mb + r) * N + n] = v;
                }
            }
        }
    } else if (mode == 0) {
#pragma unroll
        for (int mf = 0; mf < 4; mf++) {
            int mb = m0 + wr * 64 + mf * 16 + lq * 4;
            int b = mb >> LoutSh, t = mb & LoutM;
#pragma unroll
            for (int nf = 0; nf < 4; nf++) {
                int n = n0 + wc * 64 + nf * 16 + l15;
                float bv = bias[n];
                uint4 o;
                unsigned* O = (unsigned*)&o;
#pragma unroll
                for (int r = 0; r < 4; r++) {
                    float v = acc0[mf][nf][r] + acc1[mf][nf][r] * s12 + bv;
                    v = fmaxf(v, 0.f);
                    O[r] = split_pack(v);
                }
                *reinterpret_cast<uint4*>(&OutP[((size_t)b * N + n) * Lout + t]) = o;
            }
        }
    } else {  // mode 1
#pragma unroll
        for (int mf = 0; mf < 4; mf++) {
            int mb = m0 + wr * 64 + mf * 16 + lq * 4;
            int b = mb >> LoutSh, t = mb & LoutM;
#pragma unroll
            for (int nf = 0; nf < 4; nf++) {
                int n = n0 + wc * 64 + nf * 16 + l15;
                float bv = bias[n];
                float4 f;
                unsigned O[4];
#pragma unroll
                for (int r = 0; r < 4; r++) {
                    float v = acc0[mf][nf][r] + acc1[mf][nf][r] * s12 + bv;
                    ((float*)&f)[r] = v;
                    O[r] = split_pack(v);
                }
                *reinterpret_cast<float4*>(&OutF[((size_t)b * N + n) * Lout + t]) = f;
#pragma unroll
                for (int r = 0; r < 4; r++)
                    OutP[(size_t)(mb + r) * N + n] = O[r];
            }
        }
    }
}

// ||codebook_n||^2, one wave per row (fp32 exact)
__global__ __launch_bounds__(64) void cb_norm(const float* __restrict__ cb,
                                              float* __restrict__ cn2) {
    int n = blockIdx.x;
    int lane = threadIdx.x;
    float s = 0.f;
    for (int d = lane; d < 512; d += 64) {
        float v = cb[(size_t)n * 512 + d];
        s += v * v;
    }
#pragma unroll
    for (int off = 32; off; off >>= 1) s += __shfl_down(s, off);
    if (lane == 0) cn2[n] = s;
}

// argmin over (cn2[n] - 2*S[r][n]); one wave per row, first-occurrence ties
__global__ __launch_bounds__(256) void argmin_k(const float* __restrict__ S,
                                                const float* __restrict__ cn2,
                                                float* __restrict__ idxf,
                                                int* __restrict__ idxi, int rows) {
    int wid = threadIdx.x >> 6;
    int lane = threadIdx.x & 63;
    int r = blockIdx.x * 4 + wid;
    if (r >= rows) return;
    const float* srow = S + (size_t)r * 1024;
    float best = INFINITY;
    int bi = 0;
#pragma unroll
    for (int it = 0; it < 4; it++) {
        int nb = it * 256 + lane * 4;
        float4 s4 = *reinterpret_cast<const float4*>(&srow[nb]);
        float4 c4 = *reinterpret_cast<const float4*>(&cn2[nb]);
        float v;
        v = c4.x - 2.f * s4.x; if (v < best) { best = v; bi = nb + 0; }
        v = c4.y - 2.f * s4.y; if (v < best) { best = v; bi = nb + 1; }
        v = c4.z - 2.f * s4.z; if (v < best) { best = v; bi = nb + 2; }
        v = c4.w - 2.f * s4.w; if (v < best) { best = v; bi = nb + 3; }
    }
#pragma unroll
    for (int off = 32; off; off >>= 1) {
        float ov = __shfl_down(best, off);
        int oi = __shfl_down(bi, off);
        if (ov < best || (ov == best && oi < bi)) { best = ov; bi = oi; }
    }
    if (lane == 0) {
        idxf[r] = (float)bi;
        idxi[r] = bi;
    }
}

// z_q[r][:] = codebook[idx[r]][:]
__global__ __launch_bounds__(256) void gather_k(const int* __restrict__ idx,
                                                const float* __restrict__ cb,
                                                float* __restrict__ zq, int total4) {
    int g = blockIdx.x * 256 + threadIdx.x;
    if (g >= total4) return;
    int r = g >> 7;
    int d4 = g & 127;
    int id = idx[r];
    *reinterpret_cast<float4*>(&zq[(size_t)r * 512 + (size_t)d4 * 4]) =
        *reinterpret_cast<const float4*>(&cb[(size_t)id * 512 + (size_t)d4 * 4]);
}

extern "C" void kernel_launch(void* const* d_in, const int* in_sizes, int n_in,
                              void* d_out, int out_size, void* d_ws, size_t ws_size,
                              hipStream_t stream) {
    const float* x  = (const float*)d_in[0];  // (32, 256, 2048)
    const float* w1 = (const float*)d_in[1];  // (1024, 256, 4) = [n][kk]
    const float* b1 = (const float*)d_in[2];
    const float* w2 = (const float*)d_in[3];  // (512, 1024, 4)
    const float* b2 = (const float*)d_in[4];
    const float* cb = (const float*)d_in[5];  // (1024, 512)
    float* out = (float*)d_out;

    const int B = 32, Cin = 256, T = 2048, H = 1024, D = 512, Kc = 1024;
    const int T1 = 1024, T2 = 512;

    float* zq_out  = out;                       // (B*T2, D)
    float* idx_out = out + (size_t)B * T2 * D;  // (B*T2,)
    float* ze_out  = idx_out + (size_t)B * T2;  // (B, D, T2)

    // ws layout (u32 units)
    unsigned* w1p = (unsigned*)d_ws;                       // H*Cin*4
    unsigned* w2p = w1p + (size_t)H * Cin * 4;             // D*H*4
    unsigned* cbp = w2p + (size_t)D * H * 4;               // Kc*D
    float* cn2    = (float*)(cbp + (size_t)Kc * D);        // Kc
    int* idx_ws   = (int*)(cn2 + Kc);                      // B*T2
    unsigned* dyn = (unsigned*)(idx_ws + B * T2);

    size_t fixed_u32 = (size_t)H * Cin * 4 + (size_t)D * H * 4 + (size_t)Kc * D
                       + Kc + (size_t)B * T2 + 256;
    int NB = 32;
    while (NB > 1 &&
           (fixed_u32 + (size_t)NB * ((size_t)Cin * T + (size_t)H * T1 + (size_t)T2 * D))
               * 4 > ws_size)
        NB >>= 1;

    unsigned* xp = dyn;
    unsigned* hp = xp + (size_t)NB * Cin * T;
    unsigned* zp = hp + (size_t)NB * H * T1;
    float* S = (float*)hp;   // overlays hp (dead when scores run)

    split_kernel<<<(H * Cin * 4 / 4 + 255) / 256, 256, 0, stream>>>(w1, w1p, H * Cin * 4 / 4);
    split_kernel<<<(D * H * 4 / 4 + 255) / 256, 256, 0, stream>>>(w2, w2p, D * H * 4 / 4);
    split_kernel<<<(Kc * D / 4 + 255) / 256, 256, 0, stream>>>(cb, cbp, Kc * D / 4);
    cb_norm<<<Kc, 64, 0, stream>>>(cb, cn2);

    for (int b0 = 0; b0 < B; b0 += NB) {
        int nb = (B - b0 < NB) ? (B - b0) : NB;

        split_kernel<<<(nb * Cin * T / 4 + 255) / 256, 256, 0, stream>>>(
            x + (size_t)b0 * Cin * T, xp, nb * Cin * T / 4);

        // conv1 + relu -> hp (packed NCH)
        mfma_gemm<<<dim3(H / BNt, nb * T1 / BMt), 256, 0, stream>>>(
            xp, w1p, b1, hp, nullptr,
            nb * T1, H, Cin * 4, Cin, T, T1, /*LoutSh*/10, /*gather*/1, /*mode*/0);

        // conv2 -> ze (fp32 NCH) + zp (packed [m][D])
        mfma_gemm<<<dim3(D / BNt, nb * T2 / BMt), 256, 0, stream>>>(
            hp, w2p, b2, zp, ze_out + (size_t)b0 * D * T2,
            nb * T2, D, H * 4, H, T1, T2, /*LoutSh*/9, /*gather*/1, /*mode*/1);

        // scores S[m][n] = z.cb
        mfma_gemm<<<dim3(Kc / BNt, nb * T2 / BMt), 256, 0, stream>>>(
            zp, cbp, nullptr, nullptr, S,
            nb * T2, Kc, D, D, T2, T2, /*LoutSh*/9, /*gather*/0, /*mode*/2);

        argmin_k<<<(nb * T2 + 3) / 4, 256, 0, stream>>>(
            S, cn2, idx_out + (size_t)b0 * T2, idx_ws, nb * T2);

        gather_k<<<(nb * T2 * D / 4 + 255) / 256, 256, 0, stream>>>(
            idx_ws, cb, zq_out + (size_t)b0 * T2 * D, nb * T2 * D / 4);
    }
}

// Round 6
// 580.746 us; speedup vs baseline: 1.9960x; 1.0643x over previous
//
#include <hip/hip_runtime.h>
#include <hip/hip_bf16.h>

using f16x8 = __attribute__((ext_vector_type(8))) _Float16;
using f32x4 = __attribute__((ext_vector_type(4))) float;

union PackU { unsigned u; _Float16 h[2]; };

__device__ inline unsigned split_pack(float v) {
    _Float16 h0 = (_Float16)v;
    float r = (v - (float)h0) * 4096.0f;   // exact; scaled residual stays fp16-normal
    PackU p; p.h[0] = h0; p.h[1] = (_Float16)r;
    return p.u;
}

// fp32 -> packed {f16 hi, f16 lo*4096} pairs
__global__ __launch_bounds__(256) void split_kernel(const float* __restrict__ src,
                                                    unsigned* __restrict__ dst, int n4) {
    int g = blockIdx.x * 256 + threadIdx.x;
    if (g >= n4) return;
    float4 v = reinterpret_cast<const float4*>(src)[g];
    uint4 o;
    o.x = split_pack(v.x); o.y = split_pack(v.y);
    o.z = split_pack(v.z); o.w = split_pack(v.w);
    reinterpret_cast<uint4*>(dst)[g] = o;
}

#define BMt 128
#define BNt 128
#define BKt 32

// Unified split-fp16 MFMA gather-GEMM, 2-deep pipelined (dbuf LDS, 1 barrier/K-step).
// C[m][n] = sum_kk A[m][kk] * B[n][kk]   (B row-major [N][KK])
// gather: A[m][kk] = Ap[b][c][i], kk=(c,kw), i=2t-1+kw, m=(b,t)
// mode 0: OutP[b][n][Lout]+t = split_pack(relu(acc+bias))      (conv1 -> hp)
// mode 1: OutF NCH fp32 (+bias) AND OutP[m][N] packed          (conv2 -> ze, zp)
// mode 2: OutF[m][N] fp32                                      (scores)
__global__ __launch_bounds__(256, 2) void mfma_gemm(
    const unsigned* __restrict__ Ap, const unsigned* __restrict__ Bp,
    const float* __restrict__ bias,
    unsigned* __restrict__ OutP, float* __restrict__ OutF,
    int M, int N, int KK, int Cc, int L, int Lout, int LoutSh,
    int gatherMode, int mode)
{
    __shared__ uint4 As4[2][BMt * 8];   // [buf][row*8+chunk], chunk=plane*4+k/8, XOR-swizzled
    __shared__ uint4 Bs4[2][BNt * 8];

    const int tid = threadIdx.x;
    const int m0 = blockIdx.y * BMt;
    const int n0 = blockIdx.x * BNt;

    // staging mapping: thread -> (row, k-half)
    const int srow = tid >> 1;
    const int kh = tid & 1;
    const int sw_s = srow & 7;
    const int am = m0 + srow;
    const int ab = am >> LoutSh;
    const int at = am & (Lout - 1);
    const unsigned* aprow = Ap + (size_t)ab * Cc * L;
    const int ai0 = 2 * at - 1;
    const unsigned* adir = Ap + (size_t)am * KK;
    const unsigned* brow = Bp + (size_t)(n0 + srow) * KK;

    // wave mapping
    const int lane = tid & 63;
    const int wv = tid >> 6;
    const int wr = wv >> 1, wc = wv & 1;
    const int l15 = lane & 15, lq = lane >> 4;

    f32x4 acc0[4][4] = {{{0.f}}};
    f32x4 acc1[4][4] = {{{0.f}}};

    uint4 pa[4], pb[4];

    auto loadT = [&](int k0) {
        if (gatherMode) {
            int cbase = (k0 >> 2) + kh * 4;
#pragma unroll
            for (int cl = 0; cl < 4; cl++) {
                const unsigned* base = aprow + (size_t)(cbase + cl) * L;
                unsigned q0 = 0, q3 = 0;
                if (ai0 >= 0) q0 = base[ai0];           // only t==0 pads
                unsigned q1 = base[ai0 + 1];
                unsigned q2 = base[ai0 + 2];
                if (ai0 + 3 < L) q3 = base[ai0 + 3];    // only t==Lout-1 pads
                pa[cl].x = q0; pa[cl].y = q1; pa[cl].z = q2; pa[cl].w = q3;
            }
        } else {
            const uint4* s = reinterpret_cast<const uint4*>(adir + k0 + kh * 16);
            pa[0] = s[0]; pa[1] = s[1]; pa[2] = s[2]; pa[3] = s[3];
        }
        const uint4* s = reinterpret_cast<const uint4*>(brow + k0 + kh * 16);
        pb[0] = s[0]; pb[1] = s[1]; pb[2] = s[2]; pb[3] = s[3];
    };

    // repack pa/pb -> LDS buf (v_perm split, validated r4/r5)
    auto stage = [&](int buf) {
#pragma unroll
        for (int ch = 0; ch < 2; ch++) {
            uint4 w0, w1, v0, v1;
            unsigned* W0 = (unsigned*)&w0; unsigned* W1 = (unsigned*)&w1;
            unsigned* V0 = (unsigned*)&v0; unsigned* V1 = (unsigned*)&v1;
#pragma unroll
            for (int j = 0; j < 4; j++) {
                int e0 = ch * 8 + 2 * j, e1 = e0 + 1;
                unsigned lo = ((const unsigned*)&pa[e0 >> 2])[e0 & 3];
                unsigned hi = ((const unsigned*)&pa[e1 >> 2])[e1 & 3];
                W0[j] = __builtin_amdgcn_perm(hi, lo, 0x05040100u);
                W1[j] = __builtin_amdgcn_perm(hi, lo, 0x07060302u);
                lo = ((const unsigned*)&pb[e0 >> 2])[e0 & 3];
                hi = ((const unsigned*)&pb[e1 >> 2])[e1 & 3];
                V0[j] = __builtin_amdgcn_perm(hi, lo, 0x05040100u);
                V1[j] = __builtin_amdgcn_perm(hi, lo, 0x07060302u);
            }
            int kc = kh * 2 + ch;
            As4[buf][srow * 8 + ((kc) ^ sw_s)] = w0;
            As4[buf][srow * 8 + ((4 + kc) ^ sw_s)] = w1;
            Bs4[buf][srow * 8 + ((kc) ^ sw_s)] = v0;
            Bs4[buf][srow * 8 + ((4 + kc) ^ sw_s)] = v1;
        }
    };

    const int NT = KK / BKt;

    loadT(0);
    stage(0);

    for (int kt = 0; kt < NT; kt++) {
        const int cur = kt & 1;
        if (kt + 1 < NT) loadT((kt + 1) * BKt);   // issue early; lands under MFMA

        __syncthreads();   // buf[cur] writes visible to all waves

        f16x8 a0f[4], a1f[4];
#pragma unroll
        for (int mf = 0; mf < 4; mf++) {
            int row = wr * 64 + mf * 16 + l15;
            int sw = row & 7;
            a0f[mf] = *reinterpret_cast<const f16x8*>(&As4[cur][row * 8 + (lq ^ sw)]);
            a1f[mf] = *reinterpret_cast<const f16x8*>(&As4[cur][row * 8 + ((4 + lq) ^ sw)]);
        }
#pragma unroll
        for (int nf = 0; nf < 4; nf++) {
            int row = wc * 64 + nf * 16 + l15;
            int sw = row & 7;
            f16x8 b0f = *reinterpret_cast<const f16x8*>(&Bs4[cur][row * 8 + (lq ^ sw)]);
            f16x8 b1f = *reinterpret_cast<const f16x8*>(&Bs4[cur][row * 8 + ((4 + lq) ^ sw)]);
#pragma unroll
            for (int mf = 0; mf < 4; mf++) {
                acc0[mf][nf] = __builtin_amdgcn_mfma_f32_16x16x32_f16(
                    a0f[mf], b0f, acc0[mf][nf], 0, 0, 0);
                acc1[mf][nf] = __builtin_amdgcn_mfma_f32_16x16x32_f16(
                    a0f[mf], b1f, acc1[mf][nf], 0, 0, 0);
                acc1[mf][nf] = __builtin_amdgcn_mfma_f32_16x16x32_f16(
                    a1f[mf], b0f, acc1[mf][nf], 0, 0, 0);
            }
        }

        if (kt + 1 < NT) stage(cur ^ 1);   // write next tile; no conflict with buf[cur] readers
    }

    const float s12 = 1.0f / 4096.0f;
    const int LoutM = Lout - 1;

    if (mode == 2) {
#pragma unroll
        for (int mf = 0; mf < 4; mf++) {
            int mb = m0 + wr * 64 + mf * 16 + lq * 4;
#pragma unroll
            for (int nf = 0; nf < 4; nf++) {
                int n = n0 + wc * 64 + nf * 16 + l15;
#pragma unroll
                for (int r = 0; r < 4; r++) {
                    float v = acc0[mf][nf][r] + acc1[mf][nf][r] * s12;
                    OutF[(size_t)(mb + r) * N + n] = v;
                }
            }
        }
    } else if (mode == 0) {
#pragma unroll
        for (int mf = 0; mf < 4; mf++) {
            int mb = m0 + wr * 64 + mf * 16 + lq * 4;
            int b = mb >> LoutSh, t = mb & LoutM;
#pragma unroll
            for (int nf = 0; nf < 4; nf++) {
                int n = n0 + wc * 64 + nf * 16 + l15;
                float bv = bias[n];
                uint4 o;
                unsigned* O = (unsigned*)&o;
#pragma unroll
                for (int r = 0; r < 4; r++) {
                    float v = acc0[mf][nf][r] + acc1[mf][nf][r] * s12 + bv;
                    v = fmaxf(v, 0.f);
                    O[r] = split_pack(v);
                }
                *reinterpret_cast<uint4*>(&OutP[((size_t)b * N + n) * Lout + t]) = o;
            }
        }
    } else {  // mode 1
#pragma unroll
        for (int mf = 0; mf < 4; mf++) {
            int mb = m0 + wr * 64 + mf * 16 + lq * 4;
            int b = mb >> LoutSh, t = mb & LoutM;
#pragma unroll
            for (int nf = 0; nf < 4; nf++) {
                int n = n0 + wc * 64 + nf * 16 + l15;
                float bv = bias[n];
                float4 f;
                unsigned O[4];
#pragma unroll
                for (int r = 0; r < 4; r++) {
                    float v = acc0[mf][nf][r] + acc1[mf][nf][r] * s12 + bv;
                    ((float*)&f)[r] = v;
                    O[r] = split_pack(v);
                }
                *reinterpret_cast<float4*>(&OutF[((size_t)b * N + n) * Lout + t]) = f;
#pragma unroll
                for (int r = 0; r < 4; r++)
                    OutP[(size_t)(mb + r) * N + n] = O[r];
            }
        }
    }
}

// ||codebook_n||^2, one wave per row (fp32 exact)
__global__ __launch_bounds__(64) void cb_norm(const float* __restrict__ cb,
                                              float* __restrict__ cn2) {
    int n = blockIdx.x;
    int lane = threadIdx.x;
    float s = 0.f;
    for (int d = lane; d < 512; d += 64) {
        float v = cb[(size_t)n * 512 + d];
        s += v * v;
    }
#pragma unroll
    for (int off = 32; off; off >>= 1) s += __shfl_down(s, off);
    if (lane == 0) cn2[n] = s;
}

// argmin over (cn2[n] - 2*S[r][n]); one wave per row, first-occurrence ties
__global__ __launch_bounds__(256) void argmin_k(const float* __restrict__ S,
                                                const float* __restrict__ cn2,
                                                float* __restrict__ idxf,
                                                int* __restrict__ idxi, int rows) {
    int wid = threadIdx.x >> 6;
    int lane = threadIdx.x & 63;
    int r = blockIdx.x * 4 + wid;
    if (r >= rows) return;
    const float* srow = S + (size_t)r * 1024;
    float best = INFINITY;
    int bi = 0;
#pragma unroll
    for (int it = 0; it < 4; it++) {
        int nb = it * 256 + lane * 4;
        float4 s4 = *reinterpret_cast<const float4*>(&srow[nb]);
        float4 c4 = *reinterpret_cast<const float4*>(&cn2[nb]);
        float v;
        v = c4.x - 2.f * s4.x; if (v < best) { best = v; bi = nb + 0; }
        v = c4.y - 2.f * s4.y; if (v < best) { best = v; bi = nb + 1; }
        v = c4.z - 2.f * s4.z; if (v < best) { best = v; bi = nb + 2; }
        v = c4.w - 2.f * s4.w; if (v < best) { best = v; bi = nb + 3; }
    }
#pragma unroll
    for (int off = 32; off; off >>= 1) {
        float ov = __shfl_down(best, off);
        int oi = __shfl_down(bi, off);
        if (ov < best || (ov == best && oi < bi)) { best = ov; bi = oi; }
    }
    if (lane == 0) {
        idxf[r] = (float)bi;
        idxi[r] = bi;
    }
}

// z_q[r][:] = codebook[idx[r]][:]
__global__ __launch_bounds__(256) void gather_k(const int* __restrict__ idx,
                                                const float* __restrict__ cb,
                                                float* __restrict__ zq, int total4) {
    int g = blockIdx.x * 256 + threadIdx.x;
    if (g >= total4) return;
    int r = g >> 7;
    int d4 = g & 127;
    int id = idx[r];
    *reinterpret_cast<float4*>(&zq[(size_t)r * 512 + (size_t)d4 * 4]) =
        *reinterpret_cast<const float4*>(&cb[(size_t)id * 512 + (size_t)d4 * 4]);
}

extern "C" void kernel_launch(void* const* d_in, const int* in_sizes, int n_in,
                              void* d_out, int out_size, void* d_ws, size_t ws_size,
                              hipStream_t stream) {
    const float* x  = (const float*)d_in[0];  // (32, 256, 2048)
    const float* w1 = (const float*)d_in[1];  // (1024, 256, 4) = [n][kk]
    const float* b1 = (const float*)d_in[2];
    const float* w2 = (const float*)d_in[3];  // (512, 1024, 4)
    const float* b2 = (const float*)d_in[4];
    const float* cb = (const float*)d_in[5];  // (1024, 512)
    float* out = (float*)d_out;

    const int B = 32, Cin = 256, T = 2048, H = 1024, D = 512, Kc = 1024;
    const int T1 = 1024, T2 = 512;

    float* zq_out  = out;                       // (B*T2, D)
    float* idx_out = out + (size_t)B * T2 * D;  // (B*T2,)
    float* ze_out  = idx_out + (size_t)B * T2;  // (B, D, T2)

    // ws layout (u32 units)
    unsigned* w1p = (unsigned*)d_ws;                       // H*Cin*4
    unsigned* w2p = w1p + (size_t)H * Cin * 4;             // D*H*4
    unsigned* cbp = w2p + (size_t)D * H * 4;               // Kc*D
    float* cn2    = (float*)(cbp + (size_t)Kc * D);        // Kc
    int* idx_ws   = (int*)(cn2 + Kc);                      // B*T2
    unsigned* dyn = (unsigned*)(idx_ws + B * T2);

    size_t fixed_u32 = (size_t)H * Cin * 4 + (size_t)D * H * 4 + (size_t)Kc * D
                       + Kc + (size_t)B * T2 + 256;
    int NB = 32;
    while (NB > 1 &&
           (fixed_u32 + (size_t)NB * ((size_t)Cin * T + (size_t)H * T1 + (size_t)T2 * D))
               * 4 > ws_size)
        NB >>= 1;

    unsigned* xp = dyn;
    unsigned* hp = xp + (size_t)NB * Cin * T;
    unsigned* zp = hp + (size_t)NB * H * T1;
    float* S = (float*)hp;   // overlays hp (dead when scores run)

    split_kernel<<<(H * Cin * 4 / 4 + 255) / 256, 256, 0, stream>>>(w1, w1p, H * Cin * 4 / 4);
    split_kernel<<<(D * H * 4 / 4 + 255) / 256, 256, 0, stream>>>(w2, w2p, D * H * 4 / 4);
    split_kernel<<<(Kc * D / 4 + 255) / 256, 256, 0, stream>>>(cb, cbp, Kc * D / 4);
    cb_norm<<<Kc, 64, 0, stream>>>(cb, cn2);

    for (int b0 = 0; b0 < B; b0 += NB) {
        int nb = (B - b0 < NB) ? (B - b0) : NB;

        split_kernel<<<(nb * Cin * T / 4 + 255) / 256, 256, 0, stream>>>(
            x + (size_t)b0 * Cin * T, xp, nb * Cin * T / 4);

        // conv1 + relu -> hp (packed NCH)
        mfma_gemm<<<dim3(H / BNt, nb * T1 / BMt), 256, 0, stream>>>(
            xp, w1p, b1, hp, nullptr,
            nb * T1, H, Cin * 4, Cin, T, T1, /*LoutSh*/10, /*gather*/1, /*mode*/0);

        // conv2 -> ze (fp32 NCH) + zp (packed [m][D])
        mfma_gemm<<<dim3(D / BNt, nb * T2 / BMt), 256, 0, stream>>>(
            hp, w2p, b2, zp, ze_out + (size_t)b0 * D * T2,
            nb * T2, D, H * 4, H, T1, T2, /*LoutSh*/9, /*gather*/1, /*mode*/1);

        // scores S[m][n] = z.cb
        mfma_gemm<<<dim3(Kc / BNt, nb * T2 / BMt), 256, 0, stream>>>(
            zp, cbp, nullptr, nullptr, S,
            nb * T2, Kc, D, D, T2, T2, /*LoutSh*/9, /*gather*/0, /*mode*/2);

        argmin_k<<<(nb * T2 + 3) / 4, 256, 0, stream>>>(
            S, cn2, idx_out + (size_t)b0 * T2, idx_ws, nb * T2);

        gather_k<<<(nb * T2 * D / 4 + 255) / 256, 256, 0, stream>>>(
            idx_ws, cb, zq_out + (size_t)b0 * T2 * D, nb * T2 * D / 4);
    }
}

// Round 7
// 578.746 us; speedup vs baseline: 2.0029x; 1.0035x over previous
//
#include <hip/hip_runtime.h>
#include <hip/hip_bf16.h>

using f16x8 = __attribute__((ext_vector_type(8))) _Float16;
using f32x4 = __attribute__((ext_vector_type(4))) float;

union PackU { unsigned u; _Float16 h[2]; };

__device__ inline unsigned split_pack(float v) {
    _Float16 h0 = (_Float16)v;
    float r = (v - (float)h0) * 4096.0f;   // exact; scaled residual stays fp16-normal
    PackU p; p.h[0] = h0; p.h[1] = (_Float16)r;
    return p.u;
}

// fp32 -> packed {f16 hi, f16 lo*4096} pairs
__global__ __launch_bounds__(256) void split_kernel(const float* __restrict__ src,
                                                    unsigned* __restrict__ dst, int n4) {
    int g = blockIdx.x * 256 + threadIdx.x;
    if (g >= n4) return;
    float4 v = reinterpret_cast<const float4*>(src)[g];
    uint4 o;
    o.x = split_pack(v.x); o.y = split_pack(v.y);
    o.z = split_pack(v.z); o.w = split_pack(v.w);
    reinterpret_cast<uint4*>(dst)[g] = o;
}

#define BMt 128
#define BNt 128
#define BKt 32

// Unified split-fp16 MFMA gather-GEMM, 2-deep pipelined (dbuf LDS, raw barrier,
// vmcnt NOT drained at the barrier -> global prefetch overlaps MFMA).
// C[m][n] = sum_kk A[m][kk] * B[n][kk]   (B row-major [N][KK])
// gather: A[m][kk] = Ap[b][c][i], kk=(c,kw), i=2t-1+kw, m=(b,t)
// mode 0: OutP[b][n][Lout]+t = split_pack(relu(acc+bias))      (conv1 -> hp)
// mode 1: OutF NCH fp32 (+bias) AND OutP[m][N] packed          (conv2 -> ze, zp)
// mode 2: OutF[m][N] fp32                                      (scores)
__global__ __launch_bounds__(256, 2) void mfma_gemm(
    const unsigned* __restrict__ Ap, const unsigned* __restrict__ Bp,
    const float* __restrict__ bias,
    unsigned* __restrict__ OutP, float* __restrict__ OutF,
    int M, int N, int KK, int Cc, int L, int Lout, int LoutSh,
    int gatherMode, int mode)
{
    __shared__ uint4 As4[2][BMt * 8];   // [buf][row*8+chunk], chunk=plane*4+k/8, XOR-swizzled
    __shared__ uint4 Bs4[2][BNt * 8];

    const int tid = threadIdx.x;
    const int m0 = blockIdx.y * BMt;
    const int n0 = blockIdx.x * BNt;

    // staging mapping: thread -> (row, k-half)
    const int srow = tid >> 1;
    const int kh = tid & 1;
    const int sw_s = srow & 7;
    const int am = m0 + srow;
    const int ab = am >> LoutSh;
    const int at = am & (Lout - 1);
    const unsigned* aprow = Ap + (size_t)ab * Cc * L;
    const int ai0 = 2 * at - 1;
    const unsigned* adir = Ap + (size_t)am * KK;
    const unsigned* brow = Bp + (size_t)(n0 + srow) * KK;

    // wave mapping
    const int lane = tid & 63;
    const int wv = tid >> 6;
    const int wr = wv >> 1, wc = wv & 1;
    const int l15 = lane & 15, lq = lane >> 4;

    f32x4 acc0[4][4] = {{{0.f}}};
    f32x4 acc1[4][4] = {{{0.f}}};

    uint4 pa[4], pb[4];

    auto loadT = [&](int k0) {
        if (gatherMode) {
            int cbase = (k0 >> 2) + kh * 4;
#pragma unroll
            for (int cl = 0; cl < 4; cl++) {
                const unsigned* base = aprow + (size_t)(cbase + cl) * L;
                unsigned q0 = 0, q3 = 0;
                if (ai0 >= 0) q0 = base[ai0];           // only t==0 pads
                unsigned q1 = base[ai0 + 1];
                unsigned q2 = base[ai0 + 2];
                if (ai0 + 3 < L) q3 = base[ai0 + 3];    // only t==Lout-1 pads
                pa[cl].x = q0; pa[cl].y = q1; pa[cl].z = q2; pa[cl].w = q3;
            }
        } else {
            const uint4* s = reinterpret_cast<const uint4*>(adir + k0 + kh * 16);
            pa[0] = s[0]; pa[1] = s[1]; pa[2] = s[2]; pa[3] = s[3];
        }
        const uint4* s = reinterpret_cast<const uint4*>(brow + k0 + kh * 16);
        pb[0] = s[0]; pb[1] = s[1]; pb[2] = s[2]; pb[3] = s[3];
    };

    // repack pa/pb -> LDS buf (v_perm split, validated r4/r5)
    auto stage = [&](int buf) {
#pragma unroll
        for (int ch = 0; ch < 2; ch++) {
            uint4 w0, w1, v0, v1;
            unsigned* W0 = (unsigned*)&w0; unsigned* W1 = (unsigned*)&w1;
            unsigned* V0 = (unsigned*)&v0; unsigned* V1 = (unsigned*)&v1;
#pragma unroll
            for (int j = 0; j < 4; j++) {
                int e0 = ch * 8 + 2 * j, e1 = e0 + 1;
                unsigned lo = ((const unsigned*)&pa[e0 >> 2])[e0 & 3];
                unsigned hi = ((const unsigned*)&pa[e1 >> 2])[e1 & 3];
                W0[j] = __builtin_amdgcn_perm(hi, lo, 0x05040100u);
                W1[j] = __builtin_amdgcn_perm(hi, lo, 0x07060302u);
                lo = ((const unsigned*)&pb[e0 >> 2])[e0 & 3];
                hi = ((const unsigned*)&pb[e1 >> 2])[e1 & 3];
                V0[j] = __builtin_amdgcn_perm(hi, lo, 0x05040100u);
                V1[j] = __builtin_amdgcn_perm(hi, lo, 0x07060302u);
            }
            int kc = kh * 2 + ch;
            As4[buf][srow * 8 + ((kc) ^ sw_s)] = w0;
            As4[buf][srow * 8 + ((4 + kc) ^ sw_s)] = w1;
            Bs4[buf][srow * 8 + ((kc) ^ sw_s)] = v0;
            Bs4[buf][srow * 8 + ((4 + kc) ^ sw_s)] = v1;
        }
    };

    const int NT = KK / BKt;

    loadT(0);
    stage(0);

    for (int kt = 0; kt < NT; kt++) {
        const int cur = kt & 1;
        if (kt + 1 < NT) loadT((kt + 1) * BKt);   // VMEM issue; stays in flight across barrier

        // produce-side fence: drain LDS ops only (NOT vmcnt), then barrier.
        // Global prefetch remains outstanding and completes under the MFMA cluster.
        asm volatile("s_waitcnt lgkmcnt(0)\n\ts_barrier" ::: "memory");
        __builtin_amdgcn_sched_barrier(0);

        f16x8 a0f[4], a1f[4];
#pragma unroll
        for (int mf = 0; mf < 4; mf++) {
            int row = wr * 64 + mf * 16 + l15;
            int sw = row & 7;
            a0f[mf] = *reinterpret_cast<const f16x8*>(&As4[cur][row * 8 + (lq ^ sw)]);
            a1f[mf] = *reinterpret_cast<const f16x8*>(&As4[cur][row * 8 + ((4 + lq) ^ sw)]);
        }
#pragma unroll
        for (int nf = 0; nf < 4; nf++) {
            int row = wc * 64 + nf * 16 + l15;
            int sw = row & 7;
            f16x8 b0f = *reinterpret_cast<const f16x8*>(&Bs4[cur][row * 8 + (lq ^ sw)]);
            f16x8 b1f = *reinterpret_cast<const f16x8*>(&Bs4[cur][row * 8 + ((4 + lq) ^ sw)]);
#pragma unroll
            for (int mf = 0; mf < 4; mf++) {
                acc0[mf][nf] = __builtin_amdgcn_mfma_f32_16x16x32_f16(
                    a0f[mf], b0f, acc0[mf][nf], 0, 0, 0);
                acc1[mf][nf] = __builtin_amdgcn_mfma_f32_16x16x32_f16(
                    a0f[mf], b1f, acc1[mf][nf], 0, 0, 0);
                acc1[mf][nf] = __builtin_amdgcn_mfma_f32_16x16x32_f16(
                    a1f[mf], b0f, acc1[mf][nf], 0, 0, 0);
            }
        }

        if (kt + 1 < NT) stage(cur ^ 1);   // vmcnt wait lands here (after MFMA), via perm deps
    }

    const float s12 = 1.0f / 4096.0f;
    const int LoutM = Lout - 1;

    if (mode == 2) {
#pragma unroll
        for (int mf = 0; mf < 4; mf++) {
            int mb = m0 + wr * 64 + mf * 16 + lq * 4;
#pragma unroll
            for (int nf = 0; nf < 4; nf++) {
                int n = n0 + wc * 64 + nf * 16 + l15;
#pragma unroll
                for (int r = 0; r < 4; r++) {
                    float v = acc0[mf][nf][r] + acc1[mf][nf][r] * s12;
                    OutF[(size_t)(mb + r) * N + n] = v;
                }
            }
        }
    } else if (mode == 0) {
#pragma unroll
        for (int mf = 0; mf < 4; mf++) {
            int mb = m0 + wr * 64 + mf * 16 + lq * 4;
            int b = mb >> LoutSh, t = mb & LoutM;
#pragma unroll
            for (int nf = 0; nf < 4; nf++) {
                int n = n0 + wc * 64 + nf * 16 + l15;
                float bv = bias[n];
                uint4 o;
                unsigned* O = (unsigned*)&o;
#pragma unroll
                for (int r = 0; r < 4; r++) {
                    float v = acc0[mf][nf][r] + acc1[mf][nf][r] * s12 + bv;
                    v = fmaxf(v, 0.f);
                    O[r] = split_pack(v);
                }
                *reinterpret_cast<uint4*>(&OutP[((size_t)b * N + n) * Lout + t]) = o;
            }
        }
    } else {  // mode 1
#pragma unroll
        for (int mf = 0; mf < 4; mf++) {
            int mb = m0 + wr * 64 + mf * 16 + lq * 4;
            int b = mb >> LoutSh, t = mb & LoutM;
#pragma unroll
            for (int nf = 0; nf < 4; nf++) {
                int n = n0 + wc * 64 + nf * 16 + l15;
                float bv = bias[n];
                float4 f;
                unsigned O[4];
#pragma unroll
                for (int r = 0; r < 4; r++) {
                    float v = acc0[mf][nf][r] + acc1[mf][nf][r] * s12 + bv;
                    ((float*)&f)[r] = v;
                    O[r] = split_pack(v);
                }
                *reinterpret_cast<float4*>(&OutF[((size_t)b * N + n) * Lout + t]) = f;
#pragma unroll
                for (int r = 0; r < 4; r++)
                    OutP[(size_t)(mb + r) * N + n] = O[r];
            }
        }
    }
}

// ||codebook_n||^2, one wave per row (fp32 exact)
__global__ __launch_bounds__(64) void cb_norm(const float* __restrict__ cb,
                                              float* __restrict__ cn2) {
    int n = blockIdx.x;
    int lane = threadIdx.x;
    float s = 0.f;
    for (int d = lane; d < 512; d += 64) {
        float v = cb[(size_t)n * 512 + d];
        s += v * v;
    }
#pragma unroll
    for (int off = 32; off; off >>= 1) s += __shfl_down(s, off);
    if (lane == 0) cn2[n] = s;
}

// argmin over (cn2[n] - 2*S[r][n]); one wave per row, first-occurrence ties
__global__ __launch_bounds__(256) void argmin_k(const float* __restrict__ S,
                                                const float* __restrict__ cn2,
                                                float* __restrict__ idxf,
                                                int* __restrict__ idxi, int rows) {
    int wid = threadIdx.x >> 6;
    int lane = threadIdx.x & 63;
    int r = blockIdx.x * 4 + wid;
    if (r >= rows) return;
    const float* srow = S + (size_t)r * 1024;
    float best = INFINITY;
    int bi = 0;
#pragma unroll
    for (int it = 0; it < 4; it++) {
        int nb = it * 256 + lane * 4;
        float4 s4 = *reinterpret_cast<const float4*>(&srow[nb]);
        float4 c4 = *reinterpret_cast<const float4*>(&cn2[nb]);
        float v;
        v = c4.x - 2.f * s4.x; if (v < best) { best = v; bi = nb + 0; }
        v = c4.y - 2.f * s4.y; if (v < best) { best = v; bi = nb + 1; }
        v = c4.z - 2.f * s4.z; if (v < best) { best = v; bi = nb + 2; }
        v = c4.w - 2.f * s4.w; if (v < best) { best = v; bi = nb + 3; }
    }
#pragma unroll
    for (int off = 32; off; off >>= 1) {
        float ov = __shfl_down(best, off);
        int oi = __shfl_down(bi, off);
        if (ov < best || (ov == best && oi < bi)) { best = ov; bi = oi; }
    }
    if (lane == 0) {
        idxf[r] = (float)bi;
        idxi[r] = bi;
    }
}

// z_q[r][:] = codebook[idx[r]][:]
__global__ __launch_bounds__(256) void gather_k(const int* __restrict__ idx,
                                                const float* __restrict__ cb,
                                                float* __restrict__ zq, int total4) {
    int g = blockIdx.x * 256 + threadIdx.x;
    if (g >= total4) return;
    int r = g >> 7;
    int d4 = g & 127;
    int id = idx[r];
    *reinterpret_cast<float4*>(&zq[(size_t)r * 512 + (size_t)d4 * 4]) =
        *reinterpret_cast<const float4*>(&cb[(size_t)id * 512 + (size_t)d4 * 4]);
}

extern "C" void kernel_launch(void* const* d_in, const int* in_sizes, int n_in,
                              void* d_out, int out_size, void* d_ws, size_t ws_size,
                              hipStream_t stream) {
    const float* x  = (const float*)d_in[0];  // (32, 256, 2048)
    const float* w1 = (const float*)d_in[1];  // (1024, 256, 4) = [n][kk]
    const float* b1 = (const float*)d_in[2];
    const float* w2 = (const float*)d_in[3];  // (512, 1024, 4)
    const float* b2 = (const float*)d_in[4];
    const float* cb = (const float*)d_in[5];  // (1024, 512)
    float* out = (float*)d_out;

    const int B = 32, Cin = 256, T = 2048, H = 1024, D = 512, Kc = 1024;
    const int T1 = 1024, T2 = 512;

    float* zq_out  = out;                       // (B*T2, D)
    float* idx_out = out + (size_t)B * T2 * D;  // (B*T2,)
    float* ze_out  = idx_out + (size_t)B * T2;  // (B, D, T2)

    // ws layout (u32 units)
    unsigned* w1p = (unsigned*)d_ws;                       // H*Cin*4
    unsigned* w2p = w1p + (size_t)H * Cin * 4;             // D*H*4
    unsigned* cbp = w2p + (size_t)D * H * 4;               // Kc*D
    float* cn2    = (float*)(cbp + (size_t)Kc * D);        // Kc
    int* idx_ws   = (int*)(cn2 + Kc);                      // B*T2
    unsigned* dyn = (unsigned*)(idx_ws + B * T2);

    size_t fixed_u32 = (size_t)H * Cin * 4 + (size_t)D * H * 4 + (size_t)Kc * D
                       + Kc + (size_t)B * T2 + 256;
    int NB = 32;
    while (NB > 1 &&
           (fixed_u32 + (size_t)NB * ((size_t)Cin * T + (size_t)H * T1 + (size_t)T2 * D))
               * 4 > ws_size)
        NB >>= 1;

    unsigned* xp = dyn;
    unsigned* hp = xp + (size_t)NB * Cin * T;
    unsigned* zp = hp + (size_t)NB * H * T1;
    float* S = (float*)hp;   // overlays hp (dead when scores run)

    split_kernel<<<(H * Cin * 4 / 4 + 255) / 256, 256, 0, stream>>>(w1, w1p, H * Cin * 4 / 4);
    split_kernel<<<(D * H * 4 / 4 + 255) / 256, 256, 0, stream>>>(w2, w2p, D * H * 4 / 4);
    split_kernel<<<(Kc * D / 4 + 255) / 256, 256, 0, stream>>>(cb, cbp, Kc * D / 4);
    cb_norm<<<Kc, 64, 0, stream>>>(cb, cn2);

    for (int b0 = 0; b0 < B; b0 += NB) {
        int nb = (B - b0 < NB) ? (B - b0) : NB;

        split_kernel<<<(nb * Cin * T / 4 + 255) / 256, 256, 0, stream>>>(
            x + (size_t)b0 * Cin * T, xp, nb * Cin * T / 4);

        // conv1 + relu -> hp (packed NCH)
        mfma_gemm<<<dim3(H / BNt, nb * T1 / BMt), 256, 0, stream>>>(
            xp, w1p, b1, hp, nullptr,
            nb * T1, H, Cin * 4, Cin, T, T1, /*LoutSh*/10, /*gather*/1, /*mode*/0);

        // conv2 -> ze (fp32 NCH) + zp (packed [m][D])
        mfma_gemm<<<dim3(D / BNt, nb * T2 / BMt), 256, 0, stream>>>(
            hp, w2p, b2, zp, ze_out + (size_t)b0 * D * T2,
            nb * T2, D, H * 4, H, T1, T2, /*LoutSh*/9, /*gather*/1, /*mode*/1);

        // scores S[m][n] = z.cb
        mfma_gemm<<<dim3(Kc / BNt, nb * T2 / BMt), 256, 0, stream>>>(
            zp, cbp, nullptr, nullptr, S,
            nb * T2, Kc, D, D, T2, T2, /*LoutSh*/9, /*gather*/0, /*mode*/2);

        argmin_k<<<(nb * T2 + 3) / 4, 256, 0, stream>>>(
            S, cn2, idx_out + (size_t)b0 * T2, idx_ws, nb * T2);

        gather_k<<<(nb * T2 * D / 4 + 255) / 256, 256, 0, stream>>>(
            idx_ws, cb, zq_out + (size_t)b0 * T2 * D, nb * T2 * D / 4);
    }
}